// Round 10
// baseline (194.432 us; speedup 1.0000x reference)
//
#include <hip/hip_runtime.h>
#include <stdint.h>

// ---------- types ----------
typedef __bf16 bf16x8 __attribute__((ext_vector_type(8)));
typedef float  f32x4  __attribute__((ext_vector_type(4)));

__device__ __forceinline__ unsigned short f2bf(float f) {
  union { float f; unsigned int u; } v; v.f = f;
  unsigned int r = v.u + 0x7FFFu + ((v.u >> 16) & 1u);   // RNE
  return (unsigned short)(r >> 16);
}
__device__ __forceinline__ float bf2f(unsigned short b) {
  union { unsigned int u; float f; } v; v.u = ((unsigned int)b) << 16; return v.f;
}

// ---- fp8 e4m3 (OCP) encode/decode, RNE ----
__device__ __forceinline__ unsigned char f2fp8(float f) {
  f = fminf(fmaxf(f, -448.f), 448.f);
  union { float f; unsigned u; } v; v.f = f;
  unsigned s = (v.u >> 24) & 0x80;
  int e = (v.u >> 23) & 0xFF;
  unsigned m = v.u & 0x7FFFFF;
  if (e >= 121) {                       // normal
    unsigned keep = m >> 20, rest = m & 0xFFFFF;
    unsigned v8 = ((unsigned)(e - 120) << 3) | keep;
    v8 += (rest > 0x80000u) || (rest == 0x80000u && (keep & 1));
    if (v8 > 0x7E) v8 = 0x7E;           // avoid NaN encoding
    return (unsigned char)(s | v8);
  }
  if (e <= 110) return (unsigned char)s;  // rounds to 0
  unsigned M = 0x800000u | m;
  int shift = 141 - e;                  // 21..30
  unsigned keep = M >> shift;
  unsigned rest = M & ((1u << shift) - 1);
  unsigned half = 1u << (shift - 1);
  keep += (rest > half) || (rest == half && (keep & 1));
  return (unsigned char)(s | keep);
}
__device__ __forceinline__ float fp82f(unsigned char b) {
  unsigned s = (b & 0x80) ? 0x80000000u : 0u;
  int E = (b >> 3) & 0xF;
  unsigned m = b & 7;
  union { unsigned u; float f; } t;
  if (E == 0) t.f = (float)m * 0.001953125f;   // m * 2^-9
  else t.u = ((unsigned)(E + 120) << 23) | (m << 20);
  t.u |= s;
  return t.f;
}

__device__ __forceinline__ void gld_lds16(const void* g, void* l) {
  __builtin_amdgcn_global_load_lds(
      (const __attribute__((address_space(1))) void*)g,
      (__attribute__((address_space(3))) void*)l, 16, 0, 0);
}

__device__ __forceinline__ int swz(int row) { return (row & 3) ^ ((row >> 2) & 3); }

// ---------- fused: Y -> Yb + Ybt (y<16); W -> Wb (y==16); x==0,y==16 zeros stats ----------
__global__ __launch_bounds__(256) void convert_all(
    const float* __restrict__ Y, unsigned short* __restrict__ Yb,
    unsigned short* __restrict__ Ybt, const float4* __restrict__ W,
    ushort4* __restrict__ Wb, float* __restrict__ stats /*diag+l+flags*/) {
  if (blockIdx.y == 16) {
    if (blockIdx.x == 0) {  // zero diag(4096f)+l(4096f)+flags(64u)
      for (int i = threadIdx.x; i < 8256; i += 256) ((unsigned int*)stats)[i] = 0u;
    }
    const int base = blockIdx.x * 4096 + threadIdx.x;
#pragma unroll
    for (int k = 0; k < 16; k++) {
      float4 f = W[base + k * 256];
      ushort4 o;
      o.x = f2bf(f.x); o.y = f2bf(f.y); o.z = f2bf(f.z); o.w = f2bf(f.w);
      Wb[base + k * 256] = o;
    }
    return;
  }
  __shared__ unsigned short tile[64][65];
  const int r0 = blockIdx.x * 64;
  const int c0 = blockIdx.y * 64;
  const int tx = threadIdx.x & 63, ty = threadIdx.x >> 6;
#pragma unroll
  for (int k = 0; k < 16; k++) {
    const int r = ty + 4 * k;
    float f = Y[(long)(r0 + r) * 1024 + c0 + tx];
    unsigned short b = f2bf(f);
    Yb[(long)(r0 + r) * 1024 + c0 + tx] = b;
    tile[r][tx] = b;
  }
  __syncthreads();
#pragma unroll
  for (int k = 0; k < 16; k++) {
    const int c = ty + 4 * k;
    Ybt[(long)(c0 + c) * 4096 + r0 + tx] = tile[tx][c];
  }
}

// ---------- GEMM1 fused: G8 = fp8(Yb * Wb^T) + diag from quantized G; 128x64, BK=64 ----------
// R6/R9-proven structure, unchanged.
__global__ __launch_bounds__(256) void gemm1_fused(
    const unsigned short* __restrict__ A, const unsigned short* __restrict__ B,
    unsigned char* __restrict__ G8, float* __restrict__ diag) {
  __shared__ __align__(16) unsigned short smA[128 * 64];   // 16 KB
  __shared__ __align__(16) unsigned short smB[64 * 64];    // 8 KB
  const int tid = threadIdx.x, lane = tid & 63, wave = tid >> 6;
  const int waveM = wave >> 1, waveN = wave & 1;
  const long rowA0 = (long)blockIdx.y * 128;
  const long rowB0 = (long)blockIdx.x * 64;

  const unsigned short* gAq[4]; unsigned short* lAq[4];
  const unsigned short* gBq[2]; unsigned short* lBq[2];
#pragma unroll
  for (int q = 0; q < 4; q++) {
    const int c = tid + q * 256, row = c >> 3, kc = (c & 7) ^ (row & 7);
    gAq[q] = A + (rowA0 + row) * 1024 + kc * 8;
    lAq[q] = &smA[c * 8];
  }
#pragma unroll
  for (int q = 0; q < 2; q++) {
    const int c = tid + q * 256, row = c >> 3, kc = (c & 7) ^ (row & 7);
    gBq[q] = B + (rowB0 + row) * 1024 + kc * 8;
    lBq[q] = &smB[c * 8];
  }

  const unsigned short* paB = &smA[(waveM * 64 + (lane & 15)) * 64];
  const unsigned short* pbB = &smB[(waveN * 32 + (lane & 15)) * 64];
  const int g = lane >> 4, s = lane & 7;
  const int ko[2] = { ((0 * 4 + g) ^ s) * 8, ((1 * 4 + g) ^ s) * 8 };

  f32x4 acc[4][2];
#pragma unroll
  for (int i = 0; i < 4; i++)
#pragma unroll
    for (int j = 0; j < 2; j++)
#pragma unroll
      for (int r = 0; r < 4; r++) acc[i][j][r] = 0.f;

  for (int k0 = 0; k0 < 1024; k0 += 64) {
    __syncthreads();
#pragma unroll
    for (int q = 0; q < 4; q++) gld_lds16(gAq[q] + k0, lAq[q]);
#pragma unroll
    for (int q = 0; q < 2; q++) gld_lds16(gBq[q] + k0, lBq[q]);
    __syncthreads();
#pragma unroll
    for (int kk = 0; kk < 2; kk++) {
      bf16x8 af[4], bfv[2];
#pragma unroll
      for (int i = 0; i < 4; i++) af[i] = *(const bf16x8*)(paB + i * 1024 + ko[kk]);
#pragma unroll
      for (int j = 0; j < 2; j++) bfv[j] = *(const bf16x8*)(pbB + j * 1024 + ko[kk]);
#pragma unroll
      for (int mi = 0; mi < 4; mi++)
#pragma unroll
        for (int ni = 0; ni < 2; ni++)
          acc[mi][ni] = __builtin_amdgcn_mfma_f32_16x16x32_bf16(af[mi], bfv[ni], acc[mi][ni], 0, 0, 0);
    }
  }

  const long row0 = rowA0 + waveM * 64 + (lane >> 4) * 4;
  const long col0 = rowB0 + waveN * 32 + (lane & 15);
  float nsum[4][4];
#pragma unroll
  for (int mi = 0; mi < 4; mi++)
#pragma unroll
    for (int r = 0; r < 4; r++) nsum[mi][r] = 0.f;
#pragma unroll
  for (int mi = 0; mi < 4; mi++)
#pragma unroll
    for (int ni = 0; ni < 2; ni++)
#pragma unroll
      for (int r = 0; r < 4; r++) {
        unsigned char q8 = f2fp8(acc[mi][ni][r]);
        G8[(row0 + mi * 16 + r) * 1024 + col0 + ni * 16] = q8;
        float gv = fp82f(q8);
        nsum[mi][r] += gv * gv;
      }
#pragma unroll
  for (int off = 1; off < 16; off <<= 1)
#pragma unroll
    for (int mi = 0; mi < 4; mi++)
#pragma unroll
      for (int r = 0; r < 4; r++) nsum[mi][r] += __shfl_xor(nsum[mi][r], off, 64);
  if ((lane & 15) == 0) {
#pragma unroll
    for (int mi = 0; mi < 4; mi++)
#pragma unroll
      for (int r = 0; r < 4; r++)
        atomicAdd(&diag[row0 + mi * 16 + r], nsum[mi][r]);
  }
}

// ---------- GEMM2 symmetric fp8, BARRIER-FREE K-loop ----------
// No LDS staging (G8 = 4 MB, L2/L3-resident): each wave loads fragments
// directly from global (8 B/lane), 4-deep register pipeline, prefetch
// distance 4, zero __syncthreads in the loop. Epilogue: conservative
// zero-screen (acc-d > -88 => maybe-nonzero) + LDS pair-vote so all-zero
// 128x64 flag regions skip exp AND stores entirely (flag granularity ==
// store-pair granularity; gemm3 never reads unwritten poison).
__global__ __launch_bounds__(256) void gemm2_sym(
    const unsigned char* __restrict__ G8, const float* __restrict__ diag,
    unsigned short* __restrict__ P, float* __restrict__ l,
    unsigned int* __restrict__ flags) {
  int rem = blockIdx.x, br = 0;
  while (rem >= 32 - br) { rem -= 32 - br; ++br; }
  const int bc = br + rem;

  const int tid = threadIdx.x, lane = tid & 63, wave = tid >> 6;
  const int waveM = wave >> 1, waveN = wave & 1;
  const long rowA0 = (long)br * 128;
  const long rowB0 = (long)bc * 128;

  __shared__ unsigned int nzsh[4], nzmsh[4];

  // fragment base pointers: A[m = lane&15][k-bytes = kk*32 + (lane>>4)*8]
  const unsigned char* pA[4];
  const unsigned char* pB[4];
#pragma unroll
  for (int i = 0; i < 4; i++) {
    pA[i] = G8 + (rowA0 + waveM * 64 + i * 16 + (lane & 15)) * 1024 + (lane >> 4) * 8;
    pB[i] = G8 + (rowB0 + waveN * 64 + i * 16 + (lane & 15)) * 1024 + (lane >> 4) * 8;
  }

  f32x4 acc[4][4];
#pragma unroll
  for (int i = 0; i < 4; i++)
#pragma unroll
    for (int j = 0; j < 4; j++)
#pragma unroll
      for (int r = 0; r < 4; r++) acc[i][j][r] = 0.f;

  // 4-deep rotating fragment buffers; preload kk = 0..3 (32 loads in flight)
  long fa[4][4], fb[4][4];
#pragma unroll
  for (int p = 0; p < 4; p++) {
#pragma unroll
    for (int i = 0; i < 4; i++) fa[p][i] = *(const long*)(pA[i] + p * 32);
#pragma unroll
    for (int i = 0; i < 4; i++) fb[p][i] = *(const long*)(pB[i] + p * 32);
  }

  for (int it = 0; it < 32; it += 4) {
#pragma unroll
    for (int p = 0; p < 4; p++) {
#pragma unroll
      for (int mi = 0; mi < 4; mi++)
#pragma unroll
        for (int ni = 0; ni < 4; ni++)
          acc[mi][ni] = __builtin_amdgcn_mfma_f32_16x16x32_fp8_fp8(
              fa[p][mi], fb[p][ni], acc[mi][ni], 0, 0, 0);
      // prefetch kk+4 into the buffer just consumed (tail over-reads stay in ws; unused)
      const int kn = (it + p + 4) * 32;
#pragma unroll
      for (int i = 0; i < 4; i++) fa[p][i] = *(const long*)(pA[i] + kn);
#pragma unroll
      for (int i = 0; i < 4; i++) fb[p][i] = *(const long*)(pB[i] + kn);
    }
  }

  const long row0 = rowA0 + waveM * 64 + (lane >> 4) * 4;
  const long col0 = rowB0 + waveN * 64 + (lane & 15);

  float drow[4][4], dcol[4];
#pragma unroll
  for (int mi = 0; mi < 4; mi++)
#pragma unroll
    for (int r = 0; r < 4; r++) drow[mi][r] = diag[row0 + mi * 16 + r];
#pragma unroll
  for (int ni = 0; ni < 4; ni++) dcol[ni] = diag[col0 + ni * 16];

  // conservative zero screen: x <= -88 => expf(x) flushes/rounds to exactly 0 (bf16)
  bool myP = false, myM = false;
#pragma unroll
  for (int mi = 0; mi < 4; mi++)
#pragma unroll
    for (int ni = 0; ni < 4; ni++)
#pragma unroll
      for (int r = 0; r < 4; r++) {
        myP |= (acc[mi][ni][r] - drow[mi][r] > -88.0f);
        myM |= (acc[mi][ni][r] - dcol[ni]   > -88.0f);
      }
  const unsigned int wnzP = (__ballot(myP) != 0ull) ? 1u : 0u;
  const unsigned int wnzM = (__ballot(myM) != 0ull) ? 1u : 0u;
  if (lane == 0) { nzsh[wave] = wnzP; nzmsh[wave] = wnzM; }
  __syncthreads();
  const bool pairP = (nzsh[waveN] | nzsh[2 + waveN]) != 0u;         // col-half waveN, both row halves
  const bool pairM = (nzmsh[waveM * 2] | nzmsh[waveM * 2 + 1]) != 0u;

  // ---- normal epilogue (only if this 128x64 flag region has any nonzero) ----
  if (pairP) {
    if (wnzP) {
      float lsum[4][4];
#pragma unroll
      for (int mi = 0; mi < 4; mi++)
#pragma unroll
        for (int r = 0; r < 4; r++) lsum[mi][r] = 0.f;
#pragma unroll
      for (int mi = 0; mi < 4; mi++)
#pragma unroll
        for (int ni = 0; ni < 4; ni++)
#pragma unroll
          for (int r = 0; r < 4; r++) {
            float pv = __expf(acc[mi][ni][r] - drow[mi][r]);
            unsigned short p16 = f2bf(pv);
            lsum[mi][r] += bf2f(p16);
            P[(row0 + mi * 16 + r) * 4096 + col0 + ni * 16] = p16;
          }
#pragma unroll
      for (int off = 1; off < 16; off <<= 1)
#pragma unroll
        for (int mi = 0; mi < 4; mi++)
#pragma unroll
          for (int r = 0; r < 4; r++) lsum[mi][r] += __shfl_xor(lsum[mi][r], off, 64);
      if ((lane & 15) == 0) {
#pragma unroll
        for (int mi = 0; mi < 4; mi++)
#pragma unroll
          for (int r = 0; r < 4; r++)
            atomicAdd(&l[row0 + mi * 16 + r], lsum[mi][r]);
      }
    } else {
      // partner wave has nonzeros: region must be fully written -> store zeros
#pragma unroll
      for (int mi = 0; mi < 4; mi++)
#pragma unroll
        for (int ni = 0; ni < 4; ni++)
#pragma unroll
          for (int r = 0; r < 4; r++)
            P[(row0 + mi * 16 + r) * 4096 + col0 + ni * 16] = 0;
    }
    if (waveM == 0 && lane == 0) {
      const int tile = bc * 2 + waveN;
      atomicOr(&flags[br * 2 + (tile >> 5)], 1u << (tile & 31));
    }
  }

  // ---- mirror epilogue (bc > br): P[col, row] = exp(acc - d_col) ----
  if (bc > br && pairM) {
    if (wnzM) {
      float csum[4];
#pragma unroll
      for (int ni = 0; ni < 4; ni++) csum[ni] = 0.f;
#pragma unroll
      for (int mi = 0; mi < 4; mi++)
#pragma unroll
        for (int ni = 0; ni < 4; ni++) {
          ushort4 o;
          unsigned short x;
          float pv;
          pv = __expf(acc[mi][ni][0] - dcol[ni]); x = f2bf(pv); csum[ni] += bf2f(x); o.x = x;
          pv = __expf(acc[mi][ni][1] - dcol[ni]); x = f2bf(pv); csum[ni] += bf2f(x); o.y = x;
          pv = __expf(acc[mi][ni][2] - dcol[ni]); x = f2bf(pv); csum[ni] += bf2f(x); o.z = x;
          pv = __expf(acc[mi][ni][3] - dcol[ni]); x = f2bf(pv); csum[ni] += bf2f(x); o.w = x;
          *(ushort4*)(P + (col0 + ni * 16) * 4096 + row0 + mi * 16) = o;
        }
#pragma unroll
      for (int ni = 0; ni < 4; ni++) {
        csum[ni] += __shfl_xor(csum[ni], 16, 64);
        csum[ni] += __shfl_xor(csum[ni], 32, 64);
      }
      if (lane < 16) {
#pragma unroll
        for (int ni = 0; ni < 4; ni++)
          atomicAdd(&l[col0 + ni * 16], csum[ni]);
      }
    } else {
      ushort4 z; z.x = z.y = z.z = z.w = 0;
#pragma unroll
      for (int mi = 0; mi < 4; mi++)
#pragma unroll
        for (int ni = 0; ni < 4; ni++)
          *(ushort4*)(P + (col0 + ni * 16) * 4096 + row0 + mi * 16) = z;
    }
    if (waveN == 0 && lane == 0) {
      const int tile = br * 2 + waveM;
      atomicOr(&flags[bc * 2 + (tile >> 5)], 1u << (tile & 31));
    }
  }
}

// ---------- GEMM3 sparse: Z = (P @ Y) / l, skipping all-zero P tiles (exact) ----------
__global__ __launch_bounds__(256) void gemm3_sparse(
    const unsigned short* __restrict__ P, const unsigned short* __restrict__ Ybt,
    const float* __restrict__ l, const unsigned int* __restrict__ flags,
    float* __restrict__ Z) {
  __shared__ __align__(16) unsigned short smA[128 * 32];
  __shared__ __align__(16) unsigned short smB[64 * 32];
  const int tid = threadIdx.x, lane = tid & 63, wave = tid >> 6;
  const int waveM = wave >> 1, waveN = wave & 1;
  const long rowA0 = (long)blockIdx.y * 128;
  const long rowB0 = (long)blockIdx.x * 64;

  const int rS = tid >> 2;
  const int kS = (tid & 3) ^ swz(rS);
  const unsigned short* gA0 = P + (rowA0 + rS) * 4096 + kS * 8;
  const unsigned short* gA1 = gA0 + 64 * 4096;
  unsigned short* lA0 = &smA[tid * 8];
  const unsigned short* gB0 = Ybt + (rowB0 + rS) * 4096 + kS * 8;
  unsigned short* lB0 = &smB[tid * 8];

  const int ra = waveM * 64 + (lane & 15);
  const int rb = waveN * 32 + (lane & 15);
  const unsigned short* pa = &smA[(ra * 4 + ((lane >> 4) ^ swz(ra))) * 8];
  const unsigned short* pb = &smB[(rb * 4 + ((lane >> 4) ^ swz(rb))) * 8];

  const unsigned int f0 = flags[blockIdx.y * 2];
  const unsigned int f1 = flags[blockIdx.y * 2 + 1];

  f32x4 acc[4][2];
#pragma unroll
  for (int i = 0; i < 4; i++)
#pragma unroll
    for (int j = 0; j < 2; j++)
#pragma unroll
      for (int r = 0; r < 4; r++) acc[i][j][r] = 0.f;

  for (int t = 0; t < 64; ++t) {
    const unsigned int bit = (t < 32) ? ((f0 >> t) & 1u) : ((f1 >> (t - 32)) & 1u);
    if (!bit) continue;
#pragma unroll
    for (int kk = 0; kk < 2; ++kk) {
      const int k0 = t * 64 + kk * 32;
      __syncthreads();
      gld_lds16(gA0 + k0, lA0);
      gld_lds16(gA1 + k0, lA0 + 2048);
      gld_lds16(gB0 + k0, lB0);
      __syncthreads();
      bf16x8 af[4], bfv[2];
#pragma unroll
      for (int i = 0; i < 4; i++) af[i] = *(const bf16x8*)(pa + i * 512);
#pragma unroll
      for (int j = 0; j < 2; j++) bfv[j] = *(const bf16x8*)(pb + j * 512);
#pragma unroll
      for (int mi = 0; mi < 4; mi++)
#pragma unroll
        for (int ni = 0; ni < 2; ni++)
          acc[mi][ni] = __builtin_amdgcn_mfma_f32_16x16x32_bf16(af[mi], bfv[ni], acc[mi][ni], 0, 0, 0);
    }
  }

  const long row0 = rowA0 + waveM * 64 + (lane >> 4) * 4;
  const long col0 = rowB0 + waveN * 32 + (lane & 15);
#pragma unroll
  for (int mi = 0; mi < 4; mi++)
#pragma unroll
    for (int r = 0; r < 4; r++) {
      const long row = row0 + mi * 16 + r;
      const float inv = 1.f / l[row];
#pragma unroll
      for (int ni = 0; ni < 2; ni++)
        Z[row * 1024 + col0 + ni * 16] = acc[mi][ni][r] * inv;
    }
}

// ---------- launch ----------
extern "C" void kernel_launch(void* const* d_in, const int* in_sizes, int n_in,
                              void* d_out, int out_size, void* d_ws, size_t ws_size,
                              hipStream_t stream) {
  const float* Y = (const float*)d_in[0];   // 4096 x 1024
  const float* W = (const float*)d_in[1];   // 1024 x 1024
  float* Z = (float*)d_out;                 // 4096 x 1024 fp32

  uint8_t* w = (uint8_t*)d_ws;
  unsigned short* Yb   = (unsigned short*)(w);                         // 8 MB
  unsigned short* Ybt  = (unsigned short*)(w + (8ull  << 20));         // 8 MB
  unsigned short* Wb   = (unsigned short*)(w + (16ull << 20));         // 2 MB
  unsigned char*  G8   = (unsigned char*) (w + (18ull << 20));         // 4 MB fp8 4096x1024
  unsigned short* P    = (unsigned short*)(w + (26ull << 20));         // 32 MB
  float*          diag = (float*)         (w + (58ull << 20));         // 16 KB
  float*          lrow = (float*)         (w + (58ull << 20) + 16384); // 16 KB
  unsigned int*   flg  = (unsigned int*)  (w + (58ull << 20) + 32768); // 256 B

  convert_all<<<dim3(64, 17), 256, 0, stream>>>(Y, Yb, Ybt, (const float4*)W,
                                                (ushort4*)Wb, diag);

  // G8 = fp8(Y * W^T) + diag from quantized values; 128x64 tile, BK=64 (proven)
  gemm1_fused<<<dim3(16, 32), 256, 0, stream>>>(Yb, Wb, G8, diag);

  // P = exp(G8 G8^T - diag[row]); triangle grid, barrier-free register pipeline
  gemm2_sym<<<528, 256, 0, stream>>>(G8, diag, P, lrow, flg);

  // Z = (P @ Y) / l with exact zero-tile skipping
  gemm3_sparse<<<dim3(16, 32), 256, 0, stream>>>(P, Ybt, lrow, flg, Z);
}

// Round 11
// 141.565 us; speedup vs baseline: 1.3734x; 1.3734x over previous
//
#include <hip/hip_runtime.h>
#include <stdint.h>

// ---------- types ----------
typedef __bf16 bf16x8 __attribute__((ext_vector_type(8)));
typedef float  f32x4  __attribute__((ext_vector_type(4)));

__device__ __forceinline__ unsigned short f2bf(float f) {
  union { float f; unsigned int u; } v; v.f = f;
  unsigned int r = v.u + 0x7FFFu + ((v.u >> 16) & 1u);   // RNE
  return (unsigned short)(r >> 16);
}
__device__ __forceinline__ float bf2f(unsigned short b) {
  union { unsigned int u; float f; } v; v.u = ((unsigned int)b) << 16; return v.f;
}

// ---- fp8 e4m3 (OCP) encode/decode, RNE ----
__device__ __forceinline__ unsigned char f2fp8(float f) {
  f = fminf(fmaxf(f, -448.f), 448.f);
  union { float f; unsigned u; } v; v.f = f;
  unsigned s = (v.u >> 24) & 0x80;
  int e = (v.u >> 23) & 0xFF;
  unsigned m = v.u & 0x7FFFFF;
  if (e >= 121) {                       // normal
    unsigned keep = m >> 20, rest = m & 0xFFFFF;
    unsigned v8 = ((unsigned)(e - 120) << 3) | keep;
    v8 += (rest > 0x80000u) || (rest == 0x80000u && (keep & 1));
    if (v8 > 0x7E) v8 = 0x7E;           // avoid NaN encoding
    return (unsigned char)(s | v8);
  }
  if (e <= 110) return (unsigned char)s;  // rounds to 0
  unsigned M = 0x800000u | m;
  int shift = 141 - e;                  // 21..30
  unsigned keep = M >> shift;
  unsigned rest = M & ((1u << shift) - 1);
  unsigned half = 1u << (shift - 1);
  keep += (rest > half) || (rest == half && (keep & 1));
  return (unsigned char)(s | keep);
}
__device__ __forceinline__ float fp82f(unsigned char b) {
  unsigned s = (b & 0x80) ? 0x80000000u : 0u;
  int E = (b >> 3) & 0xF;
  unsigned m = b & 7;
  union { unsigned u; float f; } t;
  if (E == 0) t.f = (float)m * 0.001953125f;   // m * 2^-9
  else t.u = ((unsigned)(E + 120) << 23) | (m << 20);
  t.u |= s;
  return t.f;
}

__device__ __forceinline__ void gld_lds16(const void* g, void* l) {
  __builtin_amdgcn_global_load_lds(
      (const __attribute__((address_space(1))) void*)g,
      (__attribute__((address_space(3))) void*)l, 16, 0, 0);
}

__device__ __forceinline__ int swz(int row) { return (row & 3) ^ ((row >> 2) & 3); }

// fragment-linear G8 address: fragment (row>>4, k>>5) stored as 64 lanes x 8 B,
// lane = ((k>>3)&3)*16 + (row&15), byte = k&7  ->  coalesced wave loads in gemm2
__device__ __forceinline__ long g8f_addr(long row, long k) {
  return (row >> 4) * 16384 + (k >> 5) * 512 + ((((k >> 3) & 3) * 16) + (row & 15)) * 8 + (k & 7);
}

// ---------- fused: Y -> Yb + Ybt (y<16); W -> Wb (y==16); x==0,y==16 zeros stats ----------
__global__ __launch_bounds__(256) void convert_all(
    const float* __restrict__ Y, unsigned short* __restrict__ Yb,
    unsigned short* __restrict__ Ybt, const float4* __restrict__ W,
    ushort4* __restrict__ Wb, float* __restrict__ stats /*diag+l+flags*/) {
  if (blockIdx.y == 16) {
    if (blockIdx.x == 0) {  // zero diag(4096f)+l(4096f)+flags(64u)
      for (int i = threadIdx.x; i < 8256; i += 256) ((unsigned int*)stats)[i] = 0u;
    }
    const int base = blockIdx.x * 4096 + threadIdx.x;
#pragma unroll
    for (int k = 0; k < 16; k++) {
      float4 f = W[base + k * 256];
      ushort4 o;
      o.x = f2bf(f.x); o.y = f2bf(f.y); o.z = f2bf(f.z); o.w = f2bf(f.w);
      Wb[base + k * 256] = o;
    }
    return;
  }
  __shared__ unsigned short tile[64][65];
  const int r0 = blockIdx.x * 64;
  const int c0 = blockIdx.y * 64;
  const int tx = threadIdx.x & 63, ty = threadIdx.x >> 6;
#pragma unroll
  for (int k = 0; k < 16; k++) {
    const int r = ty + 4 * k;
    float f = Y[(long)(r0 + r) * 1024 + c0 + tx];
    unsigned short b = f2bf(f);
    Yb[(long)(r0 + r) * 1024 + c0 + tx] = b;
    tile[r][tx] = b;
  }
  __syncthreads();
#pragma unroll
  for (int k = 0; k < 16; k++) {
    const int c = ty + 4 * k;
    Ybt[(long)(c0 + c) * 4096 + r0 + tx] = tile[tx][c];
  }
}

// ---------- GEMM1 fused: G8f = fp8(Yb * Wb^T) in fragment-linear layout + diag ----------
// R6/R9-proven K-loop; epilogue stores to g8f_addr.
__global__ __launch_bounds__(256) void gemm1_fused(
    const unsigned short* __restrict__ A, const unsigned short* __restrict__ B,
    unsigned char* __restrict__ G8, float* __restrict__ diag) {
  __shared__ __align__(16) unsigned short smA[128 * 64];   // 16 KB
  __shared__ __align__(16) unsigned short smB[64 * 64];    // 8 KB
  const int tid = threadIdx.x, lane = tid & 63, wave = tid >> 6;
  const int waveM = wave >> 1, waveN = wave & 1;
  const long rowA0 = (long)blockIdx.y * 128;
  const long rowB0 = (long)blockIdx.x * 64;

  const unsigned short* gAq[4]; unsigned short* lAq[4];
  const unsigned short* gBq[2]; unsigned short* lBq[2];
#pragma unroll
  for (int q = 0; q < 4; q++) {
    const int c = tid + q * 256, row = c >> 3, kc = (c & 7) ^ (row & 7);
    gAq[q] = A + (rowA0 + row) * 1024 + kc * 8;
    lAq[q] = &smA[c * 8];
  }
#pragma unroll
  for (int q = 0; q < 2; q++) {
    const int c = tid + q * 256, row = c >> 3, kc = (c & 7) ^ (row & 7);
    gBq[q] = B + (rowB0 + row) * 1024 + kc * 8;
    lBq[q] = &smB[c * 8];
  }

  const unsigned short* paB = &smA[(waveM * 64 + (lane & 15)) * 64];
  const unsigned short* pbB = &smB[(waveN * 32 + (lane & 15)) * 64];
  const int g = lane >> 4, s = lane & 7;
  const int ko[2] = { ((0 * 4 + g) ^ s) * 8, ((1 * 4 + g) ^ s) * 8 };

  f32x4 acc[4][2];
#pragma unroll
  for (int i = 0; i < 4; i++)
#pragma unroll
    for (int j = 0; j < 2; j++)
#pragma unroll
      for (int r = 0; r < 4; r++) acc[i][j][r] = 0.f;

  for (int k0 = 0; k0 < 1024; k0 += 64) {
    __syncthreads();
#pragma unroll
    for (int q = 0; q < 4; q++) gld_lds16(gAq[q] + k0, lAq[q]);
#pragma unroll
    for (int q = 0; q < 2; q++) gld_lds16(gBq[q] + k0, lBq[q]);
    __syncthreads();
#pragma unroll
    for (int kk = 0; kk < 2; kk++) {
      bf16x8 af[4], bfv[2];
#pragma unroll
      for (int i = 0; i < 4; i++) af[i] = *(const bf16x8*)(paB + i * 1024 + ko[kk]);
#pragma unroll
      for (int j = 0; j < 2; j++) bfv[j] = *(const bf16x8*)(pbB + j * 1024 + ko[kk]);
#pragma unroll
      for (int mi = 0; mi < 4; mi++)
#pragma unroll
        for (int ni = 0; ni < 2; ni++)
          acc[mi][ni] = __builtin_amdgcn_mfma_f32_16x16x32_bf16(af[mi], bfv[ni], acc[mi][ni], 0, 0, 0);
    }
  }

  const long row0 = rowA0 + waveM * 64 + (lane >> 4) * 4;
  const long col0 = rowB0 + waveN * 32 + (lane & 15);
  float nsum[4][4];
#pragma unroll
  for (int mi = 0; mi < 4; mi++)
#pragma unroll
    for (int r = 0; r < 4; r++) nsum[mi][r] = 0.f;
#pragma unroll
  for (int mi = 0; mi < 4; mi++)
#pragma unroll
    for (int ni = 0; ni < 2; ni++)
#pragma unroll
      for (int r = 0; r < 4; r++) {
        unsigned char q8 = f2fp8(acc[mi][ni][r]);
        G8[g8f_addr(row0 + mi * 16 + r, col0 + ni * 16)] = q8;
        float gv = fp82f(q8);
        nsum[mi][r] += gv * gv;
      }
#pragma unroll
  for (int off = 1; off < 16; off <<= 1)
#pragma unroll
    for (int mi = 0; mi < 4; mi++)
#pragma unroll
      for (int r = 0; r < 4; r++) nsum[mi][r] += __shfl_xor(nsum[mi][r], off, 64);
  if ((lane & 15) == 0) {
#pragma unroll
    for (int mi = 0; mi < 4; mi++)
#pragma unroll
      for (int r = 0; r < 4; r++)
        atomicAdd(&diag[row0 + mi * 16 + r], nsum[mi][r]);
  }
}

// ---------- GEMM2 symmetric fp8, barrier-free K-loop over fragment-linear G8 ----------
// Each fragment load = ONE coalesced 512 B wave transaction (base + lane*8).
// 4-deep rotating register buffers, prefetch distance 4, no __syncthreads in loop.
// Epilogue: conservative zero-screen + pair-vote (R10, validated).
__global__ __launch_bounds__(256) void gemm2_sym(
    const unsigned char* __restrict__ G8, const float* __restrict__ diag,
    unsigned short* __restrict__ P, float* __restrict__ l,
    unsigned int* __restrict__ flags) {
  int rem = blockIdx.x, br = 0;
  while (rem >= 32 - br) { rem -= 32 - br; ++br; }
  const int bc = br + rem;

  const int tid = threadIdx.x, lane = tid & 63, wave = tid >> 6;
  const int waveM = wave >> 1, waveN = wave & 1;
  const long rowA0 = (long)br * 128;
  const long rowB0 = (long)bc * 128;

  __shared__ unsigned int nzsh[4], nzmsh[4];

  // fragment bases: group i covers rows rbA0+i (16 rows each); lane*8 within fragment
  const long rbA0 = (rowA0 >> 4) + waveM * 4;   // br*8 + waveM*4
  const long rbB0 = (rowB0 >> 4) + waveN * 4;
  const unsigned char* pA[4];
  const unsigned char* pB[4];
#pragma unroll
  for (int i = 0; i < 4; i++) {
    pA[i] = G8 + (rbA0 + i) * 16384 + lane * 8;
    pB[i] = G8 + (rbB0 + i) * 16384 + lane * 8;
  }

  f32x4 acc[4][4];
#pragma unroll
  for (int i = 0; i < 4; i++)
#pragma unroll
    for (int j = 0; j < 4; j++)
#pragma unroll
      for (int r = 0; r < 4; r++) acc[i][j][r] = 0.f;

  // 4-deep rotating fragment buffers; preload kk = 0..3 (32 coalesced loads in flight)
  long fa[4][4], fb[4][4];
#pragma unroll
  for (int p = 0; p < 4; p++) {
#pragma unroll
    for (int i = 0; i < 4; i++) fa[p][i] = *(const long*)(pA[i] + p * 512);
#pragma unroll
    for (int i = 0; i < 4; i++) fb[p][i] = *(const long*)(pB[i] + p * 512);
  }

  for (int it = 0; it < 32; it += 4) {
#pragma unroll
    for (int p = 0; p < 4; p++) {
#pragma unroll
      for (int mi = 0; mi < 4; mi++)
#pragma unroll
        for (int ni = 0; ni < 4; ni++)
          acc[mi][ni] = __builtin_amdgcn_mfma_f32_16x16x32_fp8_fp8(
              fa[p][mi], fb[p][ni], acc[mi][ni], 0, 0, 0);
      // prefetch kk+4 into the buffer just consumed (tail over-read stays in ws slack)
      const int kn = (it + p + 4) * 512;
#pragma unroll
      for (int i = 0; i < 4; i++) fa[p][i] = *(const long*)(pA[i] + kn);
#pragma unroll
      for (int i = 0; i < 4; i++) fb[p][i] = *(const long*)(pB[i] + kn);
    }
  }

  const long row0 = rowA0 + waveM * 64 + (lane >> 4) * 4;
  const long col0 = rowB0 + waveN * 64 + (lane & 15);

  float drow[4][4], dcol[4];
#pragma unroll
  for (int mi = 0; mi < 4; mi++)
#pragma unroll
    for (int r = 0; r < 4; r++) drow[mi][r] = diag[row0 + mi * 16 + r];
#pragma unroll
  for (int ni = 0; ni < 4; ni++) dcol[ni] = diag[col0 + ni * 16];

  // conservative zero screen: x <= -88 => expf(x) == 0 to bf16 for this data
  bool myP = false, myM = false;
#pragma unroll
  for (int mi = 0; mi < 4; mi++)
#pragma unroll
    for (int ni = 0; ni < 4; ni++)
#pragma unroll
      for (int r = 0; r < 4; r++) {
        myP |= (acc[mi][ni][r] - drow[mi][r] > -88.0f);
        myM |= (acc[mi][ni][r] - dcol[ni]   > -88.0f);
      }
  const unsigned int wnzP = (__ballot(myP) != 0ull) ? 1u : 0u;
  const unsigned int wnzM = (__ballot(myM) != 0ull) ? 1u : 0u;
  if (lane == 0) { nzsh[wave] = wnzP; nzmsh[wave] = wnzM; }
  __syncthreads();
  const bool pairP = (nzsh[waveN] | nzsh[2 + waveN]) != 0u;
  const bool pairM = (nzmsh[waveM * 2] | nzmsh[waveM * 2 + 1]) != 0u;

  // ---- normal epilogue (only if this 128x64 flag region has any nonzero) ----
  if (pairP) {
    if (wnzP) {
      float lsum[4][4];
#pragma unroll
      for (int mi = 0; mi < 4; mi++)
#pragma unroll
        for (int r = 0; r < 4; r++) lsum[mi][r] = 0.f;
#pragma unroll
      for (int mi = 0; mi < 4; mi++)
#pragma unroll
        for (int ni = 0; ni < 4; ni++)
#pragma unroll
          for (int r = 0; r < 4; r++) {
            float pv = __expf(acc[mi][ni][r] - drow[mi][r]);
            unsigned short p16 = f2bf(pv);
            lsum[mi][r] += bf2f(p16);
            P[(row0 + mi * 16 + r) * 4096 + col0 + ni * 16] = p16;
          }
#pragma unroll
      for (int off = 1; off < 16; off <<= 1)
#pragma unroll
        for (int mi = 0; mi < 4; mi++)
#pragma unroll
          for (int r = 0; r < 4; r++) lsum[mi][r] += __shfl_xor(lsum[mi][r], off, 64);
      if ((lane & 15) == 0) {
#pragma unroll
        for (int mi = 0; mi < 4; mi++)
#pragma unroll
          for (int r = 0; r < 4; r++)
            atomicAdd(&l[row0 + mi * 16 + r], lsum[mi][r]);
      }
    } else {
#pragma unroll
      for (int mi = 0; mi < 4; mi++)
#pragma unroll
        for (int ni = 0; ni < 4; ni++)
#pragma unroll
          for (int r = 0; r < 4; r++)
            P[(row0 + mi * 16 + r) * 4096 + col0 + ni * 16] = 0;
    }
    if (waveM == 0 && lane == 0) {
      const int tile = bc * 2 + waveN;
      atomicOr(&flags[br * 2 + (tile >> 5)], 1u << (tile & 31));
    }
  }

  // ---- mirror epilogue (bc > br): P[col, row] = exp(acc - d_col) ----
  if (bc > br && pairM) {
    if (wnzM) {
      float csum[4];
#pragma unroll
      for (int ni = 0; ni < 4; ni++) csum[ni] = 0.f;
#pragma unroll
      for (int mi = 0; mi < 4; mi++)
#pragma unroll
        for (int ni = 0; ni < 4; ni++) {
          ushort4 o;
          unsigned short x;
          float pv;
          pv = __expf(acc[mi][ni][0] - dcol[ni]); x = f2bf(pv); csum[ni] += bf2f(x); o.x = x;
          pv = __expf(acc[mi][ni][1] - dcol[ni]); x = f2bf(pv); csum[ni] += bf2f(x); o.y = x;
          pv = __expf(acc[mi][ni][2] - dcol[ni]); x = f2bf(pv); csum[ni] += bf2f(x); o.z = x;
          pv = __expf(acc[mi][ni][3] - dcol[ni]); x = f2bf(pv); csum[ni] += bf2f(x); o.w = x;
          *(ushort4*)(P + (col0 + ni * 16) * 4096 + row0 + mi * 16) = o;
        }
#pragma unroll
      for (int ni = 0; ni < 4; ni++) {
        csum[ni] += __shfl_xor(csum[ni], 16, 64);
        csum[ni] += __shfl_xor(csum[ni], 32, 64);
      }
      if (lane < 16) {
#pragma unroll
        for (int ni = 0; ni < 4; ni++)
          atomicAdd(&l[col0 + ni * 16], csum[ni]);
      }
    } else {
      ushort4 z; z.x = z.y = z.z = z.w = 0;
#pragma unroll
      for (int mi = 0; mi < 4; mi++)
#pragma unroll
        for (int ni = 0; ni < 4; ni++)
          *(ushort4*)(P + (col0 + ni * 16) * 4096 + row0 + mi * 16) = z;
    }
    if (waveN == 0 && lane == 0) {
      const int tile = br * 2 + waveM;
      atomicOr(&flags[bc * 2 + (tile >> 5)], 1u << (tile & 31));
    }
  }
}

// ---------- GEMM3 sparse: Z = (P @ Y) / l, skipping all-zero P tiles (exact) ----------
__global__ __launch_bounds__(256) void gemm3_sparse(
    const unsigned short* __restrict__ P, const unsigned short* __restrict__ Ybt,
    const float* __restrict__ l, const unsigned int* __restrict__ flags,
    float* __restrict__ Z) {
  __shared__ __align__(16) unsigned short smA[128 * 32];
  __shared__ __align__(16) unsigned short smB[64 * 32];
  const int tid = threadIdx.x, lane = tid & 63, wave = tid >> 6;
  const int waveM = wave >> 1, waveN = wave & 1;
  const long rowA0 = (long)blockIdx.y * 128;
  const long rowB0 = (long)blockIdx.x * 64;

  const int rS = tid >> 2;
  const int kS = (tid & 3) ^ swz(rS);
  const unsigned short* gA0 = P + (rowA0 + rS) * 4096 + kS * 8;
  const unsigned short* gA1 = gA0 + 64 * 4096;
  unsigned short* lA0 = &smA[tid * 8];
  const unsigned short* gB0 = Ybt + (rowB0 + rS) * 4096 + kS * 8;
  unsigned short* lB0 = &smB[tid * 8];

  const int ra = waveM * 64 + (lane & 15);
  const int rb = waveN * 32 + (lane & 15);
  const unsigned short* pa = &smA[(ra * 4 + ((lane >> 4) ^ swz(ra))) * 8];
  const unsigned short* pb = &smB[(rb * 4 + ((lane >> 4) ^ swz(rb))) * 8];

  const unsigned int f0 = flags[blockIdx.y * 2];
  const unsigned int f1 = flags[blockIdx.y * 2 + 1];

  f32x4 acc[4][2];
#pragma unroll
  for (int i = 0; i < 4; i++)
#pragma unroll
    for (int j = 0; j < 2; j++)
#pragma unroll
      for (int r = 0; r < 4; r++) acc[i][j][r] = 0.f;

  for (int t = 0; t < 64; ++t) {
    const unsigned int bit = (t < 32) ? ((f0 >> t) & 1u) : ((f1 >> (t - 32)) & 1u);
    if (!bit) continue;
#pragma unroll
    for (int kk = 0; kk < 2; ++kk) {
      const int k0 = t * 64 + kk * 32;
      __syncthreads();
      gld_lds16(gA0 + k0, lA0);
      gld_lds16(gA1 + k0, lA0 + 2048);
      gld_lds16(gB0 + k0, lB0);
      __syncthreads();
      bf16x8 af[4], bfv[2];
#pragma unroll
      for (int i = 0; i < 4; i++) af[i] = *(const bf16x8*)(pa + i * 512);
#pragma unroll
      for (int j = 0; j < 2; j++) bfv[j] = *(const bf16x8*)(pb + j * 512);
#pragma unroll
      for (int mi = 0; mi < 4; mi++)
#pragma unroll
        for (int ni = 0; ni < 2; ni++)
          acc[mi][ni] = __builtin_amdgcn_mfma_f32_16x16x32_bf16(af[mi], bfv[ni], acc[mi][ni], 0, 0, 0);
    }
  }

  const long row0 = rowA0 + waveM * 64 + (lane >> 4) * 4;
  const long col0 = rowB0 + waveN * 32 + (lane & 15);
#pragma unroll
  for (int mi = 0; mi < 4; mi++)
#pragma unroll
    for (int r = 0; r < 4; r++) {
      const long row = row0 + mi * 16 + r;
      const float inv = 1.f / l[row];
#pragma unroll
      for (int ni = 0; ni < 2; ni++)
        Z[row * 1024 + col0 + ni * 16] = acc[mi][ni][r] * inv;
    }
}

// ---------- launch ----------
extern "C" void kernel_launch(void* const* d_in, const int* in_sizes, int n_in,
                              void* d_out, int out_size, void* d_ws, size_t ws_size,
                              hipStream_t stream) {
  const float* Y = (const float*)d_in[0];   // 4096 x 1024
  const float* W = (const float*)d_in[1];   // 1024 x 1024
  float* Z = (float*)d_out;                 // 4096 x 1024 fp32

  uint8_t* w = (uint8_t*)d_ws;
  unsigned short* Yb   = (unsigned short*)(w);                         // 8 MB
  unsigned short* Ybt  = (unsigned short*)(w + (8ull  << 20));         // 8 MB
  unsigned short* Wb   = (unsigned short*)(w + (16ull << 20));         // 2 MB
  unsigned char*  G8   = (unsigned char*) (w + (18ull << 20));         // 4 MB fp8 fragment-linear
  unsigned short* P    = (unsigned short*)(w + (26ull << 20));         // 32 MB
  float*          diag = (float*)         (w + (58ull << 20));         // 16 KB
  float*          lrow = (float*)         (w + (58ull << 20) + 16384); // 16 KB
  unsigned int*   flg  = (unsigned int*)  (w + (58ull << 20) + 32768); // 256 B

  convert_all<<<dim3(64, 17), 256, 0, stream>>>(Y, Yb, Ybt, (const float4*)W,
                                                (ushort4*)Wb, diag);

  // G8f = fp8(Y * W^T) fragment-linear + diag; 128x64 tile, BK=64 (proven loop)
  gemm1_fused<<<dim3(16, 32), 256, 0, stream>>>(Yb, Wb, G8, diag);

  // P = exp(G8 G8^T - diag[row]); triangle grid, barrier-free coalesced pipeline
  gemm2_sym<<<528, 256, 0, stream>>>(G8, diag, P, lrow, flg);

  // Z = (P @ Y) / l with exact zero-tile skipping
  gemm3_sparse<<<dim3(16, 32), 256, 0, stream>>>(P, Ybt, lrow, flg, Z);
}